// Round 2
// baseline (722.609 us; speedup 1.0000x reference)
//
#include <hip/hip_runtime.h>
#include <hip/hip_bf16.h>

#define NVEC   262144
#define NLIST  1024
#define DIM    64
#define NCHUNK 64          // 64 chunks x 16 centroids
#define NGRP   32          // 2 chunks per barrier group
#define SCALE  4096.0f     // int score quantum = 1/4096
#define DELTA_INT 1600     // 2*E + margin; E <= ||c||||x||*2^-11*SCALE ~ 710 quanta

typedef __attribute__((ext_vector_type(8))) _Float16 f16x8;
typedef __attribute__((ext_vector_type(4))) float f32x4;

// ---------------------------------------------------------------------------
// K0: csq + csq*SCALE (exact fp32), zero counter, build cmat in FRAG ORDER as
// fp16 with -2^6 scale folded in (pow2: exact). chunk ch = 4KB image
// [read r 0..3][lane l][8 halves]:
//   r=0: hi k 0..31   r=1: hi k 32..63   r=2: lo k 0..31   r=3: lo k 32..63
// where w = -64*c, hi = fp16_rne(w), lo = fp16_rne(w - hi).
// assign's ds_read_b128 for read r: lane l reads ch*4096+r*1024+l*16 —
// 64 lanes read a contiguous 1KB; staging order == global_load_lds order.
// ---------------------------------------------------------------------------
__global__ __launch_bounds__(256) void prep_kernel(const float* __restrict__ cents,
                                                   float* __restrict__ csq,
                                                   float* __restrict__ csq4k,
                                                   int* __restrict__ counter,
                                                   unsigned short* __restrict__ cmat) {
    int gid = blockIdx.x * 256 + threadIdx.x;     // 0..16383
    if (gid == 0) *counter = 0;
    if (gid < NLIST) {
        const float4* p = (const float4*)(cents + (size_t)gid * DIM);
        float s = 0.f;
#pragma unroll
        for (int i = 0; i < DIM / 4; ++i) {
            float4 t = p[i];
            s += t.x * t.x + t.y * t.y + t.z * t.z + t.w * t.w;
        }
        csq[gid] = s;
        csq4k[gid] = s * SCALE;
    }
    int c   = gid >> 4;        // centroid 0..1023
    int sub = gid & 15;        // r*4 + q
    int r   = sub >> 2;
    int qq  = sub & 3;
    const float* src = cents + (size_t)c * DIM + (r & 1) * 32 + qq * 8;
    unsigned short* dst = cmat + (c >> 4) * 2048 + r * 512 + (qq * 16 + (c & 15)) * 8;
    bool hi = (r < 2);
#pragma unroll
    for (int i = 0; i < 8; ++i) {
        float v = src[i] * -64.0f;                 // exact pow2 scale
        _Float16 h = (_Float16)v;                  // RNE
        _Float16 l = (_Float16)(v - (float)h);     // RNE residual
        dst[i] = hi ? __builtin_bit_cast(unsigned short, h)
                    : __builtin_bit_cast(unsigned short, l);
    }
}

// ---------------------------------------------------------------------------
// K1: MFMA assign + fused gather. Round-0 skeleton (LDS dbuf staging, grid
// 2048, 4 waves x 2 tiles), fp16 numerics:
//   dot term = (c_h + c_l) . x_h  -> 4 MFMA / tile-chunk (was 6 bf16)
//   scales: cmat = -64*c (fp16 pair), x_h = fp16(128*x) => acc += -8192*c.x
//   C-init: acc = SCALE*csq  => final acc = SCALE*(csq - 2*dot) = score.
// Scores as ints: e = (trunc(score)<<10)+cent -> top-2 via min/max i32.
// trunc+pack is monotone for negative scores too (two's complement).
// ---------------------------------------------------------------------------
__global__ __launch_bounds__(256, 6) void assign_mfma(const float* __restrict__ vecs,
                                                      const float* __restrict__ cents,
                                                      const unsigned short* __restrict__ cmat,
                                                      const float* __restrict__ csq4k,
                                                      float* __restrict__ out,
                                                      int* __restrict__ counter,
                                                      int* __restrict__ list) {
    __shared__ __align__(16) unsigned short chunkbuf[2][2 * 2048];  // 16 KB
    __shared__ unsigned short widx[128];                            // 256 B

    const int tid  = threadIdx.x;
    const int lane = tid & 63;
    const int wave = tid >> 6;
    const int n    = lane & 15;   // vec-in-tile (B / D-col), cent (A-row)
    const int q    = lane >> 4;   // k-group; D-row group

    const int vbase = blockIdx.x * 128 + wave * 32;

    // B fragments: x_h only (fp16), 2 K-blocks of 32, 2 tiles. 16 VGPRs.
    f16x8 xh[2][2];
#pragma unroll
    for (int t = 0; t < 2; ++t) {
        const float* vp = vecs + (size_t)(vbase + t * 16 + n) * DIM + q * 8;
#pragma unroll
        for (int kb = 0; kb < 2; ++kb) {
            float4 f0 = *(const float4*)(vp + kb * 32);
            float4 f1 = *(const float4*)(vp + kb * 32 + 4);
            float vv[8] = {f0.x, f0.y, f0.z, f0.w, f1.x, f1.y, f1.z, f1.w};
#pragma unroll
            for (int i = 0; i < 8; ++i)
                xh[t][kb][i] = (_Float16)(vv[i] * 128.0f);   // exact pow2 scale, RNE cvt
        }
    }

    // stage group 0 (chunks 0,1 = 8 KB = 4 waves x 2 insts x 64 lanes x 16 B)
#pragma unroll
    for (int p = 0; p < 2; ++p) {
        int f  = wave * 2 + p;     // 0..7
        int cc = f >> 2;           // chunk within group
        int r  = f & 3;            // 1KB quarter
        const unsigned short* g = cmat + cc * 2048 + r * 512 + lane * 8;
        __builtin_amdgcn_global_load_lds(
            (const __attribute__((address_space(1))) void*)g,
            (__attribute__((address_space(3))) void*)(&chunkbuf[0][cc * 2048 + r * 512 + lane * 8]),
            16, 0, 0);
    }

    const int IMAX = 0x7FFFFFFF;
    int min1[2] = {IMAX, IMAX};
    int min2[2] = {IMAX, IMAX};

    for (int g = 0; g < NGRP; ++g) {
        __syncthreads();   // publishes buf[g&1]; drains in-flight staging
        if (g + 1 < NGRP) {
#pragma unroll
            for (int p = 0; p < 2; ++p) {
                int f  = wave * 2 + p;
                int cc = f >> 2;
                int r  = f & 3;
                const unsigned short* gp = cmat + ((g + 1) * 2 + cc) * 2048 + r * 512 + lane * 8;
                __builtin_amdgcn_global_load_lds(
                    (const __attribute__((address_space(1))) void*)gp,
                    (__attribute__((address_space(3))) void*)(&chunkbuf[(g + 1) & 1][cc * 2048 + r * 512 + lane * 8]),
                    16, 0, 0);
            }
        }
        const unsigned short* B = chunkbuf[g & 1];
#pragma unroll
        for (int cc2 = 0; cc2 < 2; ++cc2) {
            const int c = g * 2 + cc2;
            const unsigned short* Cb = B + cc2 * 2048 + lane * 8;
            f16x8 a0 = *(const f16x8*)(Cb);          // hi, k 0..31
            f16x8 a1 = *(const f16x8*)(Cb + 512);    // hi, k 32..63
            f16x8 a2 = *(const f16x8*)(Cb + 1024);   // lo, k 0..31
            f16x8 a3 = *(const f16x8*)(Cb + 1536);   // lo, k 32..63
            float4 cs = *(const float4*)(csq4k + c * 16 + q * 4);

            // C-init: acc = SCALE*csq -> final acc IS the quantized score
            f32x4 acc[2];
            acc[0] = (f32x4){cs.x, cs.y, cs.z, cs.w};
            acc[1] = acc[0];
#pragma unroll
            for (int t = 0; t < 2; ++t) acc[t] = __builtin_amdgcn_mfma_f32_16x16x32_f16(a0, xh[t][0], acc[t], 0, 0, 0);
#pragma unroll
            for (int t = 0; t < 2; ++t) acc[t] = __builtin_amdgcn_mfma_f32_16x16x32_f16(a1, xh[t][1], acc[t], 0, 0, 0);
#pragma unroll
            for (int t = 0; t < 2; ++t) acc[t] = __builtin_amdgcn_mfma_f32_16x16x32_f16(a2, xh[t][0], acc[t], 0, 0, 0);
#pragma unroll
            for (int t = 0; t < 2; ++t) acc[t] = __builtin_amdgcn_mfma_f32_16x16x32_f16(a3, xh[t][1], acc[t], 0, 0, 0);

            const int bg = c * 16 + q * 4;      // + r = centroid index (10 bits)
#pragma unroll
            for (int t = 0; t < 2; ++t) {
#pragma unroll
                for (int r = 0; r < 4; ++r) {
                    int qi = (int)acc[t][r];    // trunc, monotone (also for <0)
                    int e = (int)((((unsigned)qi) << 10) + (unsigned)(bg + r));
                    min2[t] = min(min2[t], max(min1[t], e));   // old min1!
                    min1[t] = min(min1[t], e);
                }
            }
        }
    }

    // merge top-2 across the 4 quads of each vec-column
#pragma unroll
    for (int t = 0; t < 2; ++t) {
#pragma unroll
        for (int off = 16; off <= 32; off <<= 1) {
            int o1 = __shfl_xor(min1[t], off, 64);
            int o2 = __shfl_xor(min2[t], off, 64);
            int nm2 = min(max(min1[t], o1), min(min2[t], o2));
            min1[t] = min(min1[t], o1);
            min2[t] = nm2;
        }
        if (lane < 16) {
            int slot = wave * 32 + t * 16 + lane;
            widx[slot] = (unsigned short)(min1[t] & 1023);
            if ((min2[t] >> 10) - (min1[t] >> 10) < DELTA_INT) {
                int pos = atomicAdd(counter, 1);
                list[pos] = blockIdx.x * 128 + slot;
            }
        }
    }

    __syncthreads();
    // fused gather: 128 rows x 64 floats, fully coalesced float4 stores
    const size_t obase = (size_t)blockIdx.x * 128;
#pragma unroll
    for (int gI = 0; gI < 8; ++gI) {
        int row = gI * 16 + (tid >> 4);
        int e = tid & 15;
        int idx = widx[row];
        ((float4*)out)[(obase + row) * 16 + e] =
            ((const float4*)cents)[(size_t)idx * 16 + e];
    }
}

// ---------------------------------------------------------------------------
// K2: exact fp32 rescue — block per batch of 8 flagged rows (amortizes the
// 256 KB centroid sweep 4x vs the old 2-row version; flag rate is ~5% now).
// thread t dots centroids {t, 256+t, 512+t, 768+t} for all 8 rows. Exact
// per-component fmaf chains + (a0+a1)+(a2+a3) — identical rounding to the
// verified 2-row rescue. Lexicographic (s, idx) reduction.
// ---------------------------------------------------------------------------
__global__ __launch_bounds__(256) void rescue_kernel(const float* __restrict__ vecs,
                                                     const float* __restrict__ cents,
                                                     const float* __restrict__ csq,
                                                     const int* __restrict__ counter,
                                                     const int* __restrict__ list,
                                                     float* __restrict__ out) {
    __shared__ __align__(16) float xs[8][DIM];      // 2 KB
    __shared__ float rbest[4][8];
    __shared__ int   rbi[4][8];
    __shared__ int   fin[8];

    const int nflag = *counter;
    const int tid  = threadIdx.x;
    const int lane = tid & 63;
    const int wv   = tid >> 6;

    for (int base = blockIdx.x * 8; base < nflag; base += gridDim.x * 8) {
        const int nrow = min(8, nflag - base);
        __syncthreads();                            // xs reuse guard
        if (tid < 128) {
            int r = tid >> 4, e = tid & 15;
            int rr = min(r, nrow - 1);              // tail: duplicate last row
            ((float4*)xs[r])[e] = ((const float4*)(vecs + (size_t)list[base + rr] * DIM))[e];
        }
        __syncthreads();

        float best[8]; int bidx[8];
#pragma unroll
        for (int r = 0; r < 8; ++r) { best[r] = 3.0e38f; bidx[r] = 0; }

#pragma unroll
        for (int j = 0; j < 4; ++j) {
            int c = j * 256 + tid;                  // ascending per thread
            const float4* cp = (const float4*)(cents + (size_t)c * DIM);
            float4 acc[8];
#pragma unroll
            for (int r = 0; r < 8; ++r) acc[r] = (float4){0.f, 0.f, 0.f, 0.f};
#pragma unroll
            for (int k = 0; k < DIM / 4; ++k) {
                float4 cv = cp[k];
#pragma unroll
                for (int r = 0; r < 8; ++r) {
                    float4 x = ((const float4*)xs[r])[k];
                    acc[r].x = fmaf(x.x, cv.x, acc[r].x);
                    acc[r].y = fmaf(x.y, cv.y, acc[r].y);
                    acc[r].z = fmaf(x.z, cv.z, acc[r].z);
                    acc[r].w = fmaf(x.w, cv.w, acc[r].w);
                }
            }
            float cq = csq[c];
#pragma unroll
            for (int r = 0; r < 8; ++r) {
                float d = (acc[r].x + acc[r].y) + (acc[r].z + acc[r].w);
                float s = fmaf(-2.f, d, cq);
                if (s < best[r] || (s == best[r] && c < bidx[r])) { best[r] = s; bidx[r] = c; }
            }
        }

        // wave-level lexicographic (s, idx) argmin per row
#pragma unroll
        for (int r = 0; r < 8; ++r) {
#pragma unroll
            for (int off = 1; off < 64; off <<= 1) {
                float os = __shfl_xor(best[r], off, 64);
                int   oi = __shfl_xor(bidx[r], off, 64);
                if (os < best[r] || (os == best[r] && oi < bidx[r])) { best[r] = os; bidx[r] = oi; }
            }
        }
        if (lane == 0) {
#pragma unroll
            for (int r = 0; r < 8; ++r) { rbest[wv][r] = best[r]; rbi[wv][r] = bidx[r]; }
        }
        __syncthreads();
        if (tid < 8) {
            float bb = rbest[0][tid]; int bi = rbi[0][tid];
#pragma unroll
            for (int w = 1; w < 4; ++w) {
                float s = rbest[w][tid]; int ix = rbi[w][tid];
                if (s < bb || (s == bb && ix < bi)) { bb = s; bi = ix; }
            }
            fin[tid] = bi;
        }
        __syncthreads();
        if (tid < 128) {
            int r = tid >> 4, e = tid & 15;
            if (r < nrow) {
                int v = list[base + r];
                ((float4*)(out + (size_t)v * DIM))[e] =
                    ((const float4*)(cents + (size_t)fin[r] * DIM))[e];
            }
        }
    }
}

extern "C" void kernel_launch(void* const* d_in, const int* in_sizes, int n_in,
                              void* d_out, int out_size, void* d_ws, size_t ws_size,
                              hipStream_t stream) {
    const float* vecs  = (const float*)d_in[0];
    const float* cents = (const float*)d_in[1];
    float*       out   = (float*)d_out;

    // ws layout (16B aligned)
    float*          csq     = (float*)d_ws;                                     //   4096 B
    float*          csq4k   = (float*)((char*)d_ws + 4096);                     //   4096 B
    int*            counter = (int*)((char*)d_ws + 8192);                       //    256 B
    int*            list    = (int*)((char*)d_ws + 16384);                      //   1 MB
    unsigned short* cmat    = (unsigned short*)((char*)d_ws + 16384 + 1048576); // 256 KB

    prep_kernel<<<dim3(64), dim3(256), 0, stream>>>(cents, csq, csq4k, counter, cmat);
    assign_mfma<<<dim3(2048), dim3(256), 0, stream>>>(vecs, cents, cmat, csq4k, out, counter, list);
    rescue_kernel<<<dim3(2048), dim3(256), 0, stream>>>(vecs, cents, csq, counter, list, out);
}

// Round 3
// 246.517 us; speedup vs baseline: 2.9313x; 2.9313x over previous
//
#include <hip/hip_runtime.h>
#include <hip/hip_bf16.h>

#define NVEC   262144
#define NLIST  1024
#define DIM    64
#define NCHUNK 64          // 64 chunks x 16 centroids
#define SCALE  4096.0f     // int score quantum = 1/4096
#define DELTA_INT 32       // gap threshold in quanta (7.8e-3 in d^2, ~4x worst err)

typedef __attribute__((ext_vector_type(8))) short bf16x8;
typedef __attribute__((ext_vector_type(4))) float f32x4;

__device__ __forceinline__ unsigned short bf_rne(float f) {
    unsigned int u = __float_as_uint(f);
    u += 0x7fffu + ((u >> 16) & 1u);
    return (unsigned short)(u >> 16);
}
__device__ __forceinline__ float bf_up(unsigned short s) {
    return __uint_as_float(((unsigned int)s) << 16);
}

// ---------------------------------------------------------------------------
// K0: csq + csq*SCALE (exact fp32), zero counter, build cmat in FRAG ORDER
// with -2*SCALE = -8192 (exact pow2) folded into the centroid values:
//   w = -8192*c;  hi = bf_rne(w);  lo = bf_rne(w - hi)
// chunk ch = 4KB image [frag r 0..3][lane l][8 shorts]:
//   r=0: hi k 0..31   r=1: hi k 32..63   r=2: lo k 0..31   r=3: lo k 32..63
// assign reads frag r at cmat + ch*2048 + r*512 + lane*8 (shorts) -> one base
// address + {0,1024,2048,3072}B offsets, 64 lanes = contiguous 1KB per frag.
// ---------------------------------------------------------------------------
__global__ __launch_bounds__(256) void prep_kernel(const float* __restrict__ cents,
                                                   float* __restrict__ csq,
                                                   float* __restrict__ csq4k,
                                                   int* __restrict__ counter,
                                                   unsigned short* __restrict__ cmat) {
    int gid = blockIdx.x * 256 + threadIdx.x;     // 0..16383
    if (gid == 0) *counter = 0;
    if (gid < NLIST) {
        const float4* p = (const float4*)(cents + (size_t)gid * DIM);
        float s = 0.f;
#pragma unroll
        for (int i = 0; i < DIM / 4; ++i) {
            float4 t = p[i];
            s += t.x * t.x + t.y * t.y + t.z * t.z + t.w * t.w;
        }
        csq[gid] = s;
        csq4k[gid] = s * SCALE;
    }
    int c   = gid >> 4;        // centroid 0..1023
    int sub = gid & 15;        // r*4 + q
    int r   = sub >> 2;
    int qq  = sub & 3;
    const float* src = cents + (size_t)c * DIM + (r & 1) * 32 + qq * 8;
    unsigned short* dst = cmat + (c >> 4) * 2048 + r * 512 + (qq * 16 + (c & 15)) * 8;
    bool hi = (r < 2);
#pragma unroll
    for (int i = 0; i < 8; ++i) {
        float v = src[i] * -8192.0f;               // fold -2*SCALE, exact pow2
        unsigned short h = bf_rne(v);
        dst[i] = hi ? h : bf_rne(v - bf_up(h));
    }
}

// ---------------------------------------------------------------------------
// K1: MFMA assign + fused gather. NO LDS staging, NO main-loop barriers:
// cmat (256 KB) is L2-resident; A-fragments read directly as bf16x8 global
// loads. Grid 2048 x (256,8) launch bounds -> 8 blocks/CU resident, single
// pass, 32 waves/CU; free-running waves let MFMA-phase and epilogue-phase
// waves co-issue on the same SIMD. Two A-load groups per chunk (a0/a1 feed
// 4 of 6 MFMAs before a2/a3 needed) keep VGPR under the 64 cap.
// Numerics (identical error structure to verified round-0 bf16 3-term):
//   cmat = -8192*c split hi/lo; x split hi/lo (unscaled)
//   acc init = SCALE*csq; acc += w_hi.x_hi + w_lo.x_hi + w_hi.x_lo
//   final acc = SCALE*(csq - 2*c.x) = quantized score (x^2 const dropped)
// Scores as ints: e = (trunc(score)<<10)|cent -> top-2 via min/max i32.
// ---------------------------------------------------------------------------
__global__ __launch_bounds__(256, 8) void assign_mfma(const float* __restrict__ vecs,
                                                      const float* __restrict__ cents,
                                                      const unsigned short* __restrict__ cmat,
                                                      const float* __restrict__ csq4k,
                                                      float* __restrict__ out,
                                                      int* __restrict__ counter,
                                                      int* __restrict__ list) {
    __shared__ unsigned short widx[128];                            // 256 B

    const int tid  = threadIdx.x;
    const int lane = tid & 63;
    const int wave = tid >> 6;
    const int n    = lane & 15;   // vec-in-tile (B / D-col), cent (A-row)
    const int q    = lane >> 4;   // k-group; D-row group

    const int vbase = blockIdx.x * 128 + wave * 32;

    // B fragments: x_hi/x_lo, 2 K-blocks of 32, 2 tiles. 32 VGPRs persistent.
    bf16x8 xhi[2][2], xlo[2][2];
#pragma unroll
    for (int t = 0; t < 2; ++t) {
        const float* vp = vecs + (size_t)(vbase + t * 16 + n) * DIM + q * 8;
#pragma unroll
        for (int kb = 0; kb < 2; ++kb) {
            float4 f0 = *(const float4*)(vp + kb * 32);
            float4 f1 = *(const float4*)(vp + kb * 32 + 4);
            float vv[8] = {f0.x, f0.y, f0.z, f0.w, f1.x, f1.y, f1.z, f1.w};
#pragma unroll
            for (int i = 0; i < 8; ++i) {
                unsigned short h = bf_rne(vv[i]);
                xhi[t][kb][i] = (short)h;
                xlo[t][kb][i] = (short)bf_rne(vv[i] - bf_up(h));
            }
        }
    }

    const int IMAX = 0x7FFFFFFF;
    int min1[2] = {IMAX, IMAX};
    int min2[2] = {IMAX, IMAX};

    const unsigned short* ap = cmat + lane * 8;   // +2048 shorts (4 KB) per chunk
    const float* cp = csq4k + q * 4;              // +16 floats per chunk

    for (int c = 0; c < NCHUNK; ++c) {
        float4 cs = *(const float4*)(cp);
        bf16x8 a0 = *(const bf16x8*)(ap);          // w_hi, k 0..31
        bf16x8 a1 = *(const bf16x8*)(ap + 512);    // w_hi, k 32..63

        // C-init: acc = SCALE*csq -> final acc IS the quantized score
        f32x4 acc[2];
        acc[0] = (f32x4){cs.x, cs.y, cs.z, cs.w};
        acc[1] = acc[0];

        // group 1: both terms using w_hi (a0/a1 die after these 8 MFMAs)
#pragma unroll
        for (int t = 0; t < 2; ++t) acc[t] = __builtin_amdgcn_mfma_f32_16x16x32_bf16(a0, xhi[t][0], acc[t], 0, 0, 0);
#pragma unroll
        for (int t = 0; t < 2; ++t) acc[t] = __builtin_amdgcn_mfma_f32_16x16x32_bf16(a1, xhi[t][1], acc[t], 0, 0, 0);
#pragma unroll
        for (int t = 0; t < 2; ++t) acc[t] = __builtin_amdgcn_mfma_f32_16x16x32_bf16(a0, xlo[t][0], acc[t], 0, 0, 0);
#pragma unroll
        for (int t = 0; t < 2; ++t) acc[t] = __builtin_amdgcn_mfma_f32_16x16x32_bf16(a1, xlo[t][1], acc[t], 0, 0, 0);

        // group 2: w_lo . x_hi
        bf16x8 a2 = *(const bf16x8*)(ap + 1024);   // w_lo, k 0..31
        bf16x8 a3 = *(const bf16x8*)(ap + 1536);   // w_lo, k 32..63
#pragma unroll
        for (int t = 0; t < 2; ++t) acc[t] = __builtin_amdgcn_mfma_f32_16x16x32_bf16(a2, xhi[t][0], acc[t], 0, 0, 0);
#pragma unroll
        for (int t = 0; t < 2; ++t) acc[t] = __builtin_amdgcn_mfma_f32_16x16x32_bf16(a3, xhi[t][1], acc[t], 0, 0, 0);

        const int bg = c * 16 + q * 4;      // + r = centroid index (10 bits)
#pragma unroll
        for (int t = 0; t < 2; ++t) {
#pragma unroll
            for (int r = 0; r < 4; ++r) {
                int qi = (int)acc[t][r];    // trunc, monotone within margin
                int e = (int)((((unsigned)qi) << 10) | (unsigned)(bg + r));
                min2[t] = min(min2[t], max(min1[t], e));   // old min1!
                min1[t] = min(min1[t], e);
            }
        }
        ap += 2048;
        cp += 16;
    }

    // merge top-2 across the 4 quads of each vec-column
#pragma unroll
    for (int t = 0; t < 2; ++t) {
#pragma unroll
        for (int off = 16; off <= 32; off <<= 1) {
            int o1 = __shfl_xor(min1[t], off, 64);
            int o2 = __shfl_xor(min2[t], off, 64);
            int nm2 = min(max(min1[t], o1), min(min2[t], o2));
            min1[t] = min(min1[t], o1);
            min2[t] = nm2;
        }
        if (lane < 16) {
            int slot = wave * 32 + t * 16 + lane;
            widx[slot] = (unsigned short)(min1[t] & 1023);
            if ((min2[t] >> 10) - (min1[t] >> 10) < DELTA_INT) {
                int pos = atomicAdd(counter, 1);
                list[pos] = blockIdx.x * 128 + slot;
            }
        }
    }

    __syncthreads();
    // fused gather: 128 rows x 64 floats, fully coalesced float4 stores
    const size_t obase = (size_t)blockIdx.x * 128;
#pragma unroll
    for (int gI = 0; gI < 8; ++gI) {
        int row = gI * 16 + (tid >> 4);
        int e = tid & 15;
        int idx = widx[row];
        ((float4*)out)[(obase + row) * 16 + e] =
            ((const float4*)cents)[(size_t)idx * 16 + e];
    }
}

// ---------------------------------------------------------------------------
// K2: exact fp32 rescue — block per PAIR of flagged rows; 256 threads,
// thread t dots centroids {t, 256+t, 512+t, 768+t} for both rows (cent row
// loaded once). Exact round-0 fmaf chain; lexicographic (s, idx) reduction.
// ---------------------------------------------------------------------------
__global__ __launch_bounds__(256) void rescue_kernel(const float* __restrict__ vecs,
                                                     const float* __restrict__ cents,
                                                     const float* __restrict__ csq,
                                                     const int* __restrict__ counter,
                                                     const int* __restrict__ list,
                                                     float* __restrict__ out) {
    __shared__ __align__(16) float xs[2][DIM];
    __shared__ float rbest[8];
    __shared__ int   rbi[8];
    __shared__ int   fin[2];

    const int nflag = *counter;
    const int tid  = threadIdx.x;
    const int lane = tid & 63;
    const int wv   = tid >> 6;

    for (int i = blockIdx.x * 2; i < nflag; i += gridDim.x * 2) {
        int v0 = list[i];
        int v1 = (i + 1 < nflag) ? list[i + 1] : v0;
        __syncthreads();
        if (tid < 16)       ((float4*)xs[0])[tid]      = ((const float4*)(vecs + (size_t)v0 * DIM))[tid];
        else if (tid < 32)  ((float4*)xs[1])[tid - 16] = ((const float4*)(vecs + (size_t)v1 * DIM))[tid - 16];
        __syncthreads();

        float b0 = 3.0e38f, b1 = 3.0e38f;
        int   i0 = 0, i1 = 0;
#pragma unroll
        for (int j = 0; j < 4; ++j) {
            int c = j * 256 + tid;              // ascending per thread
            const float4* cp = (const float4*)(cents + (size_t)c * DIM);
            float a0 = 0.f, a1 = 0.f, a2 = 0.f, a3 = 0.f;
            float c0 = 0.f, c1 = 0.f, c2 = 0.f, c3 = 0.f;
#pragma unroll
            for (int k = 0; k < DIM / 4; ++k) {
                float4 cv = cp[k];
                float4 x0 = ((const float4*)xs[0])[k];
                float4 x1 = ((const float4*)xs[1])[k];
                a0 = fmaf(x0.x, cv.x, a0);
                a1 = fmaf(x0.y, cv.y, a1);
                a2 = fmaf(x0.z, cv.z, a2);
                a3 = fmaf(x0.w, cv.w, a3);
                c0 = fmaf(x1.x, cv.x, c0);
                c1 = fmaf(x1.y, cv.y, c1);
                c2 = fmaf(x1.z, cv.z, c2);
                c3 = fmaf(x1.w, cv.w, c3);
            }
            float d0 = (a0 + a1) + (a2 + a3);
            float d1 = (c0 + c1) + (c2 + c3);
            float s0 = fmaf(-2.f, d0, csq[c]);
            float s1 = fmaf(-2.f, d1, csq[c]);
            if (s0 < b0) { b0 = s0; i0 = c; }
            if (s1 < b1) { b1 = s1; i1 = c; }
        }
        // wave-level lexicographic (s, idx) argmin
#pragma unroll
        for (int off = 1; off < 64; off <<= 1) {
            float os = __shfl_xor(b0, off, 64);
            int   oi = __shfl_xor(i0, off, 64);
            if (os < b0 || (os == b0 && oi < i0)) { b0 = os; i0 = oi; }
            float ps = __shfl_xor(b1, off, 64);
            int   pi = __shfl_xor(i1, off, 64);
            if (ps < b1 || (ps == b1 && pi < i1)) { b1 = ps; i1 = pi; }
        }
        if (lane == 0) {
            rbest[wv] = b0;     rbi[wv] = i0;
            rbest[wv + 4] = b1; rbi[wv + 4] = i1;
        }
        __syncthreads();
        if (tid < 2) {
            float bb = rbest[tid * 4 + 0]; int bi = rbi[tid * 4 + 0];
#pragma unroll
            for (int w = 1; w < 4; ++w) {
                float s = rbest[tid * 4 + w]; int ix = rbi[tid * 4 + w];
                if (s < bb || (s == bb && ix < bi)) { bb = s; bi = ix; }
            }
            fin[tid] = bi;
        }
        __syncthreads();
        int bi0 = fin[0], bi1 = fin[1];
        if (tid < 16)
            ((float4*)(out + (size_t)v0 * DIM))[tid] =
                ((const float4*)(cents + (size_t)bi0 * DIM))[tid];
        else if (tid < 32)
            ((float4*)(out + (size_t)v1 * DIM))[tid - 16] =
                ((const float4*)(cents + (size_t)bi1 * DIM))[tid - 16];
    }
}

extern "C" void kernel_launch(void* const* d_in, const int* in_sizes, int n_in,
                              void* d_out, int out_size, void* d_ws, size_t ws_size,
                              hipStream_t stream) {
    const float* vecs  = (const float*)d_in[0];
    const float* cents = (const float*)d_in[1];
    float*       out   = (float*)d_out;

    // ws layout (16B aligned)
    float*          csq     = (float*)d_ws;                                     //   4096 B
    float*          csq4k   = (float*)((char*)d_ws + 4096);                     //   4096 B
    int*            counter = (int*)((char*)d_ws + 8192);                       //    256 B
    int*            list    = (int*)((char*)d_ws + 16384);                      //   1 MB
    unsigned short* cmat    = (unsigned short*)((char*)d_ws + 16384 + 1048576); // 256 KB

    prep_kernel<<<dim3(64), dim3(256), 0, stream>>>(cents, csq, csq4k, counter, cmat);
    assign_mfma<<<dim3(2048), dim3(256), 0, stream>>>(vecs, cents, cmat, csq4k, out, counter, list);
    rescue_kernel<<<dim3(2048), dim3(256), 0, stream>>>(vecs, cents, csq, counter, list, out);
}

// Round 4
// 228.680 us; speedup vs baseline: 3.1599x; 1.0780x over previous
//
#include <hip/hip_runtime.h>
#include <hip/hip_bf16.h>

#define NVEC   262144
#define NLIST  1024
#define DIM    64
#define NCHUNK 64          // 64 chunks x 16 centroids
#define NGRP   32          // 2 chunks per barrier group
#define SCALE  4096.0f     // score quantum = 1/4096 (= acc ulp at 2^23)
#define MAGIC  10485760.0f // 2^23 + 2^21: pins acc exponent -> bits are monotone
#define DELTA_INT 64       // gap threshold in quanta >= 2x worst total err (~12q)

typedef __attribute__((ext_vector_type(8))) short bf16x8;
typedef __attribute__((ext_vector_type(4))) float f32x4;

__device__ __forceinline__ unsigned short bf_rne(float f) {
    unsigned int u = __float_as_uint(f);
    u += 0x7fffu + ((u >> 16) & 1u);
    return (unsigned short)(u >> 16);
}
__device__ __forceinline__ float bf_up(unsigned short s) {
    return __uint_as_float(((unsigned int)s) << 16);
}

// ---------------------------------------------------------------------------
// K0: csq (exact, for rescue) + csq4k = SCALE*csq + MAGIC (assign C-init),
// zero counter, build cmat in FRAG ORDER with -2*SCALE = -8192 folded in:
//   w = -8192*c;  hi = bf_rne(w);  lo = bf_rne(w - hi)
// chunk ch = 4KB image [frag r 0..3][lane l][8 shorts]:
//   r=0: hi k 0..31   r=1: hi k 32..63   r=2: lo k 0..31   r=3: lo k 32..63
// assign's ds_read_b128 for frag r: lane l reads ch*4096+r*1024+l*16 —
// 64 lanes read a contiguous 1KB; staging order == global_load_lds order.
// ---------------------------------------------------------------------------
__global__ __launch_bounds__(256) void prep_kernel(const float* __restrict__ cents,
                                                   float* __restrict__ csq,
                                                   float* __restrict__ csq4k,
                                                   int* __restrict__ counter,
                                                   unsigned short* __restrict__ cmat) {
    int gid = blockIdx.x * 256 + threadIdx.x;     // 0..16383
    if (gid == 0) *counter = 0;
    if (gid < NLIST) {
        const float4* p = (const float4*)(cents + (size_t)gid * DIM);
        float s = 0.f;
#pragma unroll
        for (int i = 0; i < DIM / 4; ++i) {
            float4 t = p[i];
            s += t.x * t.x + t.y * t.y + t.z * t.z + t.w * t.w;
        }
        csq[gid] = s;
        csq4k[gid] = fmaf(s, SCALE, MAGIC);
    }
    int c   = gid >> 4;        // centroid 0..1023
    int sub = gid & 15;        // r*4 + q
    int r   = sub >> 2;
    int qq  = sub & 3;
    const float* src = cents + (size_t)c * DIM + (r & 1) * 32 + qq * 8;
    unsigned short* dst = cmat + (c >> 4) * 2048 + r * 512 + (qq * 16 + (c & 15)) * 8;
    bool hi = (r < 2);
#pragma unroll
    for (int i = 0; i < 8; ++i) {
        float v = src[i] * -8192.0f;               // fold -2*SCALE, exact pow2
        unsigned short h = bf_rne(v);
        dst[i] = hi ? h : bf_rne(v - bf_up(h));
    }
}

// ---------------------------------------------------------------------------
// K1: MFMA assign + fused gather. Round-0 skeleton (LDS dbuf staging, grid
// 2048, 4 waves x 2 tiles/wave, 6 blocks/CU). Numerics:
//   cmat = -8192*c split hi/lo (bf16 3-term); x split hi/lo (unscaled)
//   acc init = SCALE*csq + MAGIC; acc += w_hi.x_hi + w_lo.x_hi + w_hi.x_lo
//   final acc in [2^23, 2^24): exponent + mantissa bit22 constant -> raw
//   float bits are a monotone unsigned encoding of the quantized score.
// Epilogue per score (4 VALU, no cvt): e = (bits<<10)+cent (v_lshl_add_u32),
// then unsigned top-2 via min/max/min.
// ---------------------------------------------------------------------------
__global__ __launch_bounds__(256, 6) void assign_mfma(const float* __restrict__ vecs,
                                                      const float* __restrict__ cents,
                                                      const unsigned short* __restrict__ cmat,
                                                      const float* __restrict__ csq4k,
                                                      float* __restrict__ out,
                                                      int* __restrict__ counter,
                                                      int* __restrict__ list) {
    __shared__ __align__(16) unsigned short chunkbuf[2][2 * 2048];  // 16 KB
    __shared__ unsigned short widx[128];                            // 256 B

    const int tid  = threadIdx.x;
    const int lane = tid & 63;
    const int wave = tid >> 6;
    const int n    = lane & 15;   // vec-in-tile (B / D-col), cent (A-row)
    const int q    = lane >> 4;   // k-group; D-row group

    const int vbase = blockIdx.x * 128 + wave * 32;

    // B fragments: x_hi/x_lo, 2 K-blocks of 32, 2 tiles. 32 VGPRs.
    bf16x8 xhi[2][2], xlo[2][2];
#pragma unroll
    for (int t = 0; t < 2; ++t) {
        const float* vp = vecs + (size_t)(vbase + t * 16 + n) * DIM + q * 8;
#pragma unroll
        for (int kb = 0; kb < 2; ++kb) {
            float4 f0 = *(const float4*)(vp + kb * 32);
            float4 f1 = *(const float4*)(vp + kb * 32 + 4);
            float vv[8] = {f0.x, f0.y, f0.z, f0.w, f1.x, f1.y, f1.z, f1.w};
#pragma unroll
            for (int i = 0; i < 8; ++i) {
                unsigned short h = bf_rne(vv[i]);
                xhi[t][kb][i] = (short)h;
                xlo[t][kb][i] = (short)bf_rne(vv[i] - bf_up(h));
            }
        }
    }

    // stage group 0 (chunks 0,1 = 8 KB = 4 waves x 2 insts x 64 lanes x 16 B)
#pragma unroll
    for (int p = 0; p < 2; ++p) {
        int f  = wave * 2 + p;     // 0..7
        int cc = f >> 2;           // chunk within group
        int r  = f & 3;            // 1KB quarter
        const unsigned short* g = cmat + cc * 2048 + r * 512 + lane * 8;
        __builtin_amdgcn_global_load_lds(
            (const __attribute__((address_space(1))) void*)g,
            (__attribute__((address_space(3))) void*)(&chunkbuf[0][cc * 2048 + r * 512 + lane * 8]),
            16, 0, 0);
    }

    const unsigned UMAX = 0xFFFFFFFFu;
    unsigned min1[2] = {UMAX, UMAX};
    unsigned min2[2] = {UMAX, UMAX};

    for (int g = 0; g < NGRP; ++g) {
        __syncthreads();   // publishes buf[g&1]; drains in-flight staging
        if (g + 1 < NGRP) {
#pragma unroll
            for (int p = 0; p < 2; ++p) {
                int f  = wave * 2 + p;
                int cc = f >> 2;
                int r  = f & 3;
                const unsigned short* gp = cmat + ((g + 1) * 2 + cc) * 2048 + r * 512 + lane * 8;
                __builtin_amdgcn_global_load_lds(
                    (const __attribute__((address_space(1))) void*)gp,
                    (__attribute__((address_space(3))) void*)(&chunkbuf[(g + 1) & 1][cc * 2048 + r * 512 + lane * 8]),
                    16, 0, 0);
            }
        }
        const unsigned short* B = chunkbuf[g & 1];
#pragma unroll
        for (int cc2 = 0; cc2 < 2; ++cc2) {
            const int c = g * 2 + cc2;
            const unsigned short* Cb = B + cc2 * 2048 + lane * 8;
            bf16x8 a0 = *(const bf16x8*)(Cb);          // w_hi, k 0..31
            bf16x8 a1 = *(const bf16x8*)(Cb + 512);    // w_hi, k 32..63
            bf16x8 a2 = *(const bf16x8*)(Cb + 1024);   // w_lo, k 0..31
            bf16x8 a3 = *(const bf16x8*)(Cb + 1536);   // w_lo, k 32..63
            float4 cs = *(const float4*)(csq4k + c * 16 + q * 4);

            // C-init: acc = SCALE*csq + MAGIC -> final bits encode the score
            f32x4 acc[2];
            acc[0] = (f32x4){cs.x, cs.y, cs.z, cs.w};
            acc[1] = acc[0];
#pragma unroll
            for (int t = 0; t < 2; ++t) acc[t] = __builtin_amdgcn_mfma_f32_16x16x32_bf16(a0, xhi[t][0], acc[t], 0, 0, 0);
#pragma unroll
            for (int t = 0; t < 2; ++t) acc[t] = __builtin_amdgcn_mfma_f32_16x16x32_bf16(a1, xhi[t][1], acc[t], 0, 0, 0);
#pragma unroll
            for (int t = 0; t < 2; ++t) acc[t] = __builtin_amdgcn_mfma_f32_16x16x32_bf16(a2, xhi[t][0], acc[t], 0, 0, 0);
#pragma unroll
            for (int t = 0; t < 2; ++t) acc[t] = __builtin_amdgcn_mfma_f32_16x16x32_bf16(a3, xhi[t][1], acc[t], 0, 0, 0);
#pragma unroll
            for (int t = 0; t < 2; ++t) acc[t] = __builtin_amdgcn_mfma_f32_16x16x32_bf16(a0, xlo[t][0], acc[t], 0, 0, 0);
#pragma unroll
            for (int t = 0; t < 2; ++t) acc[t] = __builtin_amdgcn_mfma_f32_16x16x32_bf16(a1, xlo[t][1], acc[t], 0, 0, 0);

            const unsigned bg = (unsigned)(c * 16 + q * 4); // + r = centroid idx
#pragma unroll
            for (int t = 0; t < 2; ++t) {
#pragma unroll
                for (int r = 0; r < 4; ++r) {
                    // exponent+bit22 of acc are constant -> monotone unsigned
                    unsigned e = (__float_as_uint(acc[t][r]) << 10) + (bg + (unsigned)r);
                    min2[t] = min(min2[t], max(min1[t], e));   // old min1!
                    min1[t] = min(min1[t], e);
                }
            }
        }
    }

    // merge top-2 across the 4 quads of each vec-column
#pragma unroll
    for (int t = 0; t < 2; ++t) {
#pragma unroll
        for (int off = 16; off <= 32; off <<= 1) {
            unsigned o1 = (unsigned)__shfl_xor((int)min1[t], off, 64);
            unsigned o2 = (unsigned)__shfl_xor((int)min2[t], off, 64);
            unsigned nm2 = min(max(min1[t], o1), min(min2[t], o2));
            min1[t] = min(min1[t], o1);
            min2[t] = nm2;
        }
        if (lane < 16) {
            int slot = wave * 32 + t * 16 + lane;
            widx[slot] = (unsigned short)(min1[t] & 1023u);
            if ((min2[t] >> 10) - (min1[t] >> 10) < (unsigned)DELTA_INT) {
                int pos = atomicAdd(counter, 1);
                list[pos] = blockIdx.x * 128 + slot;
            }
        }
    }

    __syncthreads();
    // fused gather: 128 rows x 64 floats, fully coalesced float4 stores
    const size_t obase = (size_t)blockIdx.x * 128;
#pragma unroll
    for (int gI = 0; gI < 8; ++gI) {
        int row = gI * 16 + (tid >> 4);
        int e = tid & 15;
        int idx = widx[row];
        ((float4*)out)[(obase + row) * 16 + e] =
            ((const float4*)cents)[(size_t)idx * 16 + e];
    }
}

// ---------------------------------------------------------------------------
// K2: exact fp32 rescue — block per PAIR of flagged rows; 256 threads,
// thread t dots centroids {t, 256+t, 512+t, 768+t} for both rows (cent row
// loaded once). Exact fmaf chain; lexicographic (s, idx) reduction.
// ---------------------------------------------------------------------------
__global__ __launch_bounds__(256) void rescue_kernel(const float* __restrict__ vecs,
                                                     const float* __restrict__ cents,
                                                     const float* __restrict__ csq,
                                                     const int* __restrict__ counter,
                                                     const int* __restrict__ list,
                                                     float* __restrict__ out) {
    __shared__ __align__(16) float xs[2][DIM];
    __shared__ float rbest[8];
    __shared__ int   rbi[8];
    __shared__ int   fin[2];

    const int nflag = *counter;
    const int tid  = threadIdx.x;
    const int lane = tid & 63;
    const int wv   = tid >> 6;

    for (int i = blockIdx.x * 2; i < nflag; i += gridDim.x * 2) {
        int v0 = list[i];
        int v1 = (i + 1 < nflag) ? list[i + 1] : v0;
        __syncthreads();
        if (tid < 16)       ((float4*)xs[0])[tid]      = ((const float4*)(vecs + (size_t)v0 * DIM))[tid];
        else if (tid < 32)  ((float4*)xs[1])[tid - 16] = ((const float4*)(vecs + (size_t)v1 * DIM))[tid - 16];
        __syncthreads();

        float b0 = 3.0e38f, b1 = 3.0e38f;
        int   i0 = 0, i1 = 0;
#pragma unroll
        for (int j = 0; j < 4; ++j) {
            int c = j * 256 + tid;              // ascending per thread
            const float4* cp = (const float4*)(cents + (size_t)c * DIM);
            float a0 = 0.f, a1 = 0.f, a2 = 0.f, a3 = 0.f;
            float c0 = 0.f, c1 = 0.f, c2 = 0.f, c3 = 0.f;
#pragma unroll
            for (int k = 0; k < DIM / 4; ++k) {
                float4 cv = cp[k];
                float4 x0 = ((const float4*)xs[0])[k];
                float4 x1 = ((const float4*)xs[1])[k];
                a0 = fmaf(x0.x, cv.x, a0);
                a1 = fmaf(x0.y, cv.y, a1);
                a2 = fmaf(x0.z, cv.z, a2);
                a3 = fmaf(x0.w, cv.w, a3);
                c0 = fmaf(x1.x, cv.x, c0);
                c1 = fmaf(x1.y, cv.y, c1);
                c2 = fmaf(x1.z, cv.z, c2);
                c3 = fmaf(x1.w, cv.w, c3);
            }
            float d0 = (a0 + a1) + (a2 + a3);
            float d1 = (c0 + c1) + (c2 + c3);
            float s0 = fmaf(-2.f, d0, csq[c]);
            float s1 = fmaf(-2.f, d1, csq[c]);
            if (s0 < b0) { b0 = s0; i0 = c; }
            if (s1 < b1) { b1 = s1; i1 = c; }
        }
        // wave-level lexicographic (s, idx) argmin
#pragma unroll
        for (int off = 1; off < 64; off <<= 1) {
            float os = __shfl_xor(b0, off, 64);
            int   oi = __shfl_xor(i0, off, 64);
            if (os < b0 || (os == b0 && oi < i0)) { b0 = os; i0 = oi; }
            float ps = __shfl_xor(b1, off, 64);
            int   pi = __shfl_xor(i1, off, 64);
            if (ps < b1 || (ps == b1 && pi < i1)) { b1 = ps; i1 = pi; }
        }
        if (lane == 0) {
            rbest[wv] = b0;     rbi[wv] = i0;
            rbest[wv + 4] = b1; rbi[wv + 4] = i1;
        }
        __syncthreads();
        if (tid < 2) {
            float bb = rbest[tid * 4 + 0]; int bi = rbi[tid * 4 + 0];
#pragma unroll
            for (int w = 1; w < 4; ++w) {
                float s = rbest[tid * 4 + w]; int ix = rbi[tid * 4 + w];
                if (s < bb || (s == bb && ix < bi)) { bb = s; bi = ix; }
            }
            fin[tid] = bi;
        }
        __syncthreads();
        int bi0 = fin[0], bi1 = fin[1];
        if (tid < 16)
            ((float4*)(out + (size_t)v0 * DIM))[tid] =
                ((const float4*)(cents + (size_t)bi0 * DIM))[tid];
        else if (tid < 32)
            ((float4*)(out + (size_t)v1 * DIM))[tid - 16] =
                ((const float4*)(cents + (size_t)bi1 * DIM))[tid - 16];
    }
}

extern "C" void kernel_launch(void* const* d_in, const int* in_sizes, int n_in,
                              void* d_out, int out_size, void* d_ws, size_t ws_size,
                              hipStream_t stream) {
    const float* vecs  = (const float*)d_in[0];
    const float* cents = (const float*)d_in[1];
    float*       out   = (float*)d_out;

    // ws layout (16B aligned)
    float*          csq     = (float*)d_ws;                                     //   4096 B
    float*          csq4k   = (float*)((char*)d_ws + 4096);                     //   4096 B
    int*            counter = (int*)((char*)d_ws + 8192);                       //    256 B
    int*            list    = (int*)((char*)d_ws + 16384);                      //   1 MB
    unsigned short* cmat    = (unsigned short*)((char*)d_ws + 16384 + 1048576); // 256 KB

    prep_kernel<<<dim3(64), dim3(256), 0, stream>>>(cents, csq, csq4k, counter, cmat);
    assign_mfma<<<dim3(2048), dim3(256), 0, stream>>>(vecs, cents, cmat, csq4k, out, counter, list);
    rescue_kernel<<<dim3(2048), dim3(256), 0, stream>>>(vecs, cents, csq, counter, list, out);
}